// Round 1
// baseline (668.338 us; speedup 1.0000x reference)
//
#include <hip/hip_runtime.h>
#include <math.h>

#define NHEADS 16
#define HDIM 128
#define BQ 32
#define BK 32
#define KSTRIDE 132   // 128 + 4 pad: row-to-row bank offset = 4 -> conflict-free patterns
#define PSTRIDE 40    // 16B-aligned rows, bank offset 8
#define SCALE 0.08838834764831845f  // 1/sqrt(128)

__launch_bounds__(256, 2)
__global__ void varlen_attn_kernel(const float* __restrict__ Q,
                                   const float* __restrict__ K,
                                   const float* __restrict__ V,
                                   const int* __restrict__ cu,
                                   float* __restrict__ Out,
                                   int T, int ncu) {
  __shared__ float Qs[BQ * KSTRIDE];
  __shared__ float Ks[BK * KSTRIDE];
  __shared__ float Vs[BK * KSTRIDE];
  __shared__ float Ps[BQ * PSTRIDE];
  __shared__ int klos[BQ];

  const int t = threadIdx.x;
  const int h = blockIdx.y;
  const int q0 = blockIdx.x * BQ;

  // ---- stage Q tile (32 rows x 128) ----
  {
    const int row = t >> 3;
    const int dbase = (t & 7) * 4;       // lanes 0..7 cover 128B contiguous; 2-way LDS write aliasing (free)
    int tok = q0 + row; if (tok >= T) tok = T - 1;
    const float* src = Q + ((size_t)tok * NHEADS + h) * HDIM;
    float* dst = Qs + row * KSTRIDE;
#pragma unroll
    for (int i = 0; i < 4; ++i) {
      const int d = dbase + 32 * i;
      *(float4*)(dst + d) = *(const float4*)(src + d);
    }
  }
  // per-row segment start (valid K range is [klo, tok] since cu_q == cu_k)
  if (t < BQ) {
    const int tok = q0 + t;
    int lo = 0;
    for (int i = 1; i < ncu; ++i) {
      const int c = cu[i];
      if (c <= tok) lo = c;
    }
    klos[t] = lo;
  }
  __syncthreads();

  const int rg = t >> 4;   // 0..15 -> rows rg, rg+16
  const int cg = t & 15;   // 0..15 -> cols cg, cg+16 of the K tile
  const int r0 = rg, r1 = rg + 16;
  const int tok0 = q0 + r0, tok1 = q0 + r1;
  const int klo0 = klos[r0], klo1 = klos[r1];
  const int kstart = klos[0] & ~(BK - 1);
  const int kend = (q0 + BQ - 1 < T - 1) ? (q0 + BQ - 1) : (T - 1);

  float m0 = -1e30f, m1 = -1e30f, l0 = 0.f, l1 = 0.f;
  float4 o00 = make_float4(0.f,0.f,0.f,0.f), o01 = o00, o10 = o00, o11 = o00;
  const int d0 = cg * 4, d1 = 64 + cg * 4;   // O d-slices: banks 4*cg -> 2-way max (free)

  for (int kt = kstart; kt <= kend; kt += BK) {
    // ---- stage K/V tile ----
    {
      const int row = t >> 3;
      const int dbase = (t & 7) * 4;
      int ktok = kt + row; if (ktok >= T) ktok = T - 1;
      const float* ksrc = K + ((size_t)ktok * NHEADS + h) * HDIM;
      const float* vsrc = V + ((size_t)ktok * NHEADS + h) * HDIM;
      float* kdst = Ks + row * KSTRIDE;
      float* vdst = Vs + row * KSTRIDE;
#pragma unroll
      for (int i = 0; i < 4; ++i) {
        const int d = dbase + 32 * i;
        *(float4*)(kdst + d) = *(const float4*)(ksrc + d);
        *(float4*)(vdst + d) = *(const float4*)(vsrc + d);
      }
    }
    __syncthreads();

    // ---- QK^T: 2x2 register tile per thread ----
    float s00 = 0.f, s01 = 0.f, s10 = 0.f, s11 = 0.f;
    const float* qr0 = Qs + r0 * KSTRIDE;
    const float* qr1 = Qs + r1 * KSTRIDE;
    const float* kc0 = Ks + cg * KSTRIDE;
    const float* kc1 = Ks + (cg + 16) * KSTRIDE;
#pragma unroll 8
    for (int kk = 0; kk < HDIM; kk += 4) {
      const float4 a0 = *(const float4*)(qr0 + kk);
      const float4 a1 = *(const float4*)(qr1 + kk);
      const float4 b0 = *(const float4*)(kc0 + kk);
      const float4 b1 = *(const float4*)(kc1 + kk);
      s00 += a0.x*b0.x + a0.y*b0.y + a0.z*b0.z + a0.w*b0.w;
      s01 += a0.x*b1.x + a0.y*b1.y + a0.z*b1.z + a0.w*b1.w;
      s10 += a1.x*b0.x + a1.y*b0.y + a1.z*b0.z + a1.w*b0.w;
      s11 += a1.x*b1.x + a1.y*b1.y + a1.z*b1.z + a1.w*b1.w;
    }

    const int c0 = kt + cg, c1 = kt + cg + 16;
    const bool v00 = (c0 >= klo0) && (c0 <= tok0);
    const bool v01 = (c1 >= klo0) && (c1 <= tok0);
    const bool v10 = (c0 >= klo1) && (c0 <= tok1);
    const bool v11 = (c1 >= klo1) && (c1 <= tok1);
    s00 = v00 ? s00 * SCALE : -1e30f;
    s01 = v01 ? s01 * SCALE : -1e30f;
    s10 = v10 ? s10 * SCALE : -1e30f;
    s11 = v11 ? s11 * SCALE : -1e30f;

    // ---- online softmax (row = 16-lane group reduction) ----
    float tm0 = fmaxf(s00, s01), tm1 = fmaxf(s10, s11);
#pragma unroll
    for (int off = 1; off < 16; off <<= 1) {
      tm0 = fmaxf(tm0, __shfl_xor(tm0, off));
      tm1 = fmaxf(tm1, __shfl_xor(tm1, off));
    }
    const float mn0 = fmaxf(m0, tm0), mn1 = fmaxf(m1, tm1);
    const float al0 = __expf(m0 - mn0), al1 = __expf(m1 - mn1);
    // explicit valid-mask on p: avoids exp(0)=1 artifacts on fully-masked tiles
    const float p00 = v00 ? __expf(s00 - mn0) : 0.f;
    const float p01 = v01 ? __expf(s01 - mn0) : 0.f;
    const float p10 = v10 ? __expf(s10 - mn1) : 0.f;
    const float p11 = v11 ? __expf(s11 - mn1) : 0.f;
    float rs0 = p00 + p01, rs1 = p10 + p11;
#pragma unroll
    for (int off = 1; off < 16; off <<= 1) {
      rs0 += __shfl_xor(rs0, off);
      rs1 += __shfl_xor(rs1, off);
    }
    l0 = l0 * al0 + rs0;
    l1 = l1 * al1 + rs1;
    m0 = mn0; m1 = mn1;

    Ps[r0 * PSTRIDE + cg]      = p00;
    Ps[r0 * PSTRIDE + cg + 16] = p01;
    Ps[r1 * PSTRIDE + cg]      = p10;
    Ps[r1 * PSTRIDE + cg + 16] = p11;

    o00.x *= al0; o00.y *= al0; o00.z *= al0; o00.w *= al0;
    o01.x *= al0; o01.y *= al0; o01.z *= al0; o01.w *= al0;
    o10.x *= al1; o10.y *= al1; o10.z *= al1; o10.w *= al1;
    o11.x *= al1; o11.y *= al1; o11.z *= al1; o11.w *= al1;
    __syncthreads();  // Ps visible to the whole block

    // ---- PV: O[r][d] += sum_c P[r][c] * V[c][d] ----
#pragma unroll
    for (int c = 0; c < BK; c += 4) {
      const float4 p0 = *(const float4*)(Ps + r0 * PSTRIDE + c);
      const float4 p1 = *(const float4*)(Ps + r1 * PSTRIDE + c);
      const float pa[4] = {p0.x, p0.y, p0.z, p0.w};
      const float pb[4] = {p1.x, p1.y, p1.z, p1.w};
#pragma unroll
      for (int j = 0; j < 4; ++j) {
        const float* vrow = Vs + (c + j) * KSTRIDE;
        const float4 va = *(const float4*)(vrow + d0);
        const float4 vb = *(const float4*)(vrow + d1);
        o00.x += pa[j]*va.x; o00.y += pa[j]*va.y; o00.z += pa[j]*va.z; o00.w += pa[j]*va.w;
        o01.x += pa[j]*vb.x; o01.y += pa[j]*vb.y; o01.z += pa[j]*vb.z; o01.w += pa[j]*vb.w;
        o10.x += pb[j]*va.x; o10.y += pb[j]*va.y; o10.z += pb[j]*va.z; o10.w += pb[j]*va.w;
        o11.x += pb[j]*vb.x; o11.y += pb[j]*vb.y; o11.z += pb[j]*vb.z; o11.w += pb[j]*vb.w;
      }
    }
    __syncthreads();  // before next tile overwrites Ks/Vs/Ps
  }

  // ---- epilogue: normalize + store ----
  const float inv0 = 1.f / l0, inv1 = 1.f / l1;
  if (tok0 < T) {
    float* dst = Out + ((size_t)tok0 * NHEADS + h) * HDIM;
    float4 w0 = make_float4(o00.x*inv0, o00.y*inv0, o00.z*inv0, o00.w*inv0);
    float4 w1 = make_float4(o01.x*inv0, o01.y*inv0, o01.z*inv0, o01.w*inv0);
    *(float4*)(dst + d0) = w0;
    *(float4*)(dst + d1) = w1;
  }
  if (tok1 < T) {
    float* dst = Out + ((size_t)tok1 * NHEADS + h) * HDIM;
    float4 w0 = make_float4(o10.x*inv1, o10.y*inv1, o10.z*inv1, o10.w*inv1);
    float4 w1 = make_float4(o11.x*inv1, o11.y*inv1, o11.z*inv1, o11.w*inv1);
    *(float4*)(dst + d0) = w0;
    *(float4*)(dst + d1) = w1;
  }
}

extern "C" void kernel_launch(void* const* d_in, const int* in_sizes, int n_in,
                              void* d_out, int out_size, void* d_ws, size_t ws_size,
                              hipStream_t stream) {
  const float* Q = (const float*)d_in[0];
  const float* K = (const float*)d_in[1];
  const float* V = (const float*)d_in[2];
  const int* cu  = (const int*)d_in[3];   // seqlen_q (== seqlen_k)
  float* out = (float*)d_out;
  const int T = in_sizes[0] / (NHEADS * HDIM);
  const int ncu = in_sizes[3];
  dim3 grid((T + BQ - 1) / BQ, NHEADS);
  varlen_attn_kernel<<<grid, 256, 0, stream>>>(Q, K, V, cu, out, T, ncu);
}

// Round 2
// 246.199 us; speedup vs baseline: 2.7146x; 2.7146x over previous
//
#include <hip/hip_runtime.h>

#define NHEADS 16
#define HDIM 128
#define BQ 64          // q rows per block (16 per wave)
#define BK 64          // k tile width
#define KSP 136        // Ks row stride (bf16 elems): 272 B = 68 banks, 16B aligned
#define KP 72          // Vt/Ps row stride (bf16 elems): 144 B = 36 banks, 16B aligned
#define SCL2 0.12751740487817725f   // (1/sqrt(128)) * log2(e)

typedef float f32x4 __attribute__((ext_vector_type(4)));
typedef short bf16x8 __attribute__((ext_vector_type(8)));
typedef unsigned int u32x4 __attribute__((ext_vector_type(4)));
typedef unsigned int u32x2 __attribute__((ext_vector_type(2)));

// round-to-nearest-even f32 -> bf16, packed pair (inputs are finite randn: no NaN guard)
__device__ __forceinline__ unsigned pk2(float a, float b) {
  unsigned ua = __builtin_bit_cast(unsigned, a);
  unsigned ub = __builtin_bit_cast(unsigned, b);
  ua = (ua + 0x7fffu + ((ua >> 16) & 1u)) >> 16;
  ub = (ub + 0x7fffu + ((ub >> 16) & 1u)) >> 16;
  return ua | (ub << 16);
}

__launch_bounds__(256, 3)   // 3 blocks/CU (LDS-limited anyway at 44 KB)
__global__ void varlen_attn_mfma(const float* __restrict__ Q,
                                 const float* __restrict__ K,
                                 const float* __restrict__ V,
                                 const int* __restrict__ cu,
                                 float* __restrict__ Out,
                                 int T, int ncu) {
  __shared__ __align__(16) unsigned short Ks[BK * KSP];     // K tile, row-major [k][d]
  __shared__ __align__(16) unsigned short Vt[HDIM * KP];    // V tile transposed [d][k]
  __shared__ __align__(16) unsigned short Ps[4][16 * KP];   // per-wave P [q][k]

  const int t = (int)threadIdx.x;
  const int w = t >> 6;        // wave 0..3
  const int l = t & 63;        // lane
  const int lam = l & 15;      // q-column within wave tile
  const int g = l >> 4;        // quad
  const int h = (int)blockIdx.y;
  const int q0 = (int)blockIdx.x * BQ;

  const int qtok = q0 + 16 * w + lam;
  const int qcl = qtok < T ? qtok : T - 1;

  // per-lane segment start; block-level k range start
  int klo = 0, klo0 = 0;
  for (int i = 1; i < ncu - 1; ++i) {
    int c = cu[i];
    if (c <= qcl) klo = c;
    if (c <= q0) klo0 = c;
  }
  const int kstart = klo0 & ~(BK - 1);
  int kend = q0 + BQ - 1; if (kend > T - 1) kend = T - 1;
  const int qmaxw = q0 + 16 * w + 15;   // last q row this wave owns

  // ---- Q B-fragments, kept in registers (B[k][n]: lane holds Q[q=lam][dc*32+g*8+j]) ----
  bf16x8 qf[4];
  {
    const float* qp = Q + ((size_t)qcl * NHEADS + h) * HDIM + g * 8;
#pragma unroll
    for (int dc = 0; dc < 4; ++dc) {
      f32x4 a = *(const f32x4*)(qp + dc * 32);
      f32x4 b = *(const f32x4*)(qp + dc * 32 + 4);
      union { u32x4 u; bf16x8 v; } cvt;
      cvt.u = (u32x4){pk2(a[0], a[1]), pk2(a[2], a[3]), pk2(b[0], b[1]), pk2(b[2], b[3])};
      qf[dc] = cvt.v;
    }
  }

  f32x4 acc[8];   // O^T accum: acc[dt] row=4g+reg -> d=dt*16+4g+reg, col=lam -> q
#pragma unroll
  for (int i = 0; i < 8; ++i) acc[i] = (f32x4){0.f, 0.f, 0.f, 0.f};
  float m2 = -1e30f, ll = 0.f;   // online-softmax state in log2 domain, per q=lam

  for (int kt = kstart; kt <= kend; kt += BK) {
    __syncthreads();   // previous tile's LDS reads complete before overwrite

    // ---- stage K tile: [64][128] fp32 -> bf16 LDS, 16B ds_writes ----
    {
      const int row = t >> 2;
      const int db = (t & 3) * 32;
      int ktok = kt + row; if (ktok > T - 1) ktok = T - 1;
      const float* kp = K + ((size_t)ktok * NHEADS + h) * HDIM + db;
      unsigned short* dst = &Ks[row * KSP + db];
#pragma unroll
      for (int i = 0; i < 4; ++i) {
        f32x4 a = *(const f32x4*)(kp + i * 8);
        f32x4 b = *(const f32x4*)(kp + i * 8 + 4);
        *(u32x4*)(dst + i * 8) =
            (u32x4){pk2(a[0], a[1]), pk2(a[2], a[3]), pk2(b[0], b[1]), pk2(b[2], b[3])};
      }
    }
    // ---- stage V tile transposed: Vt[d][k]; wave w covers k in [kt+16w, kt+16w+16) ----
    {
#pragma unroll
      for (int c = 0; c < 2; ++c) {
        const int kb = kt + 16 * w + 8 * c;
#pragma unroll
        for (int dh = 0; dh < 2; ++dh) {
          const int d = dh * 64 + l;
          float vv[8];
#pragma unroll
          for (int j = 0; j < 8; ++j) {
            int ktok = kb + j; if (ktok > T - 1) ktok = T - 1;
            vv[j] = V[((size_t)ktok * NHEADS + h) * HDIM + d];
          }
          *(u32x4*)(&Vt[d * KP + 16 * w + 8 * c]) =
              (u32x4){pk2(vv[0], vv[1]), pk2(vv[2], vv[3]), pk2(vv[4], vv[5]), pk2(vv[6], vv[7])};
        }
      }
    }
    __syncthreads();

    if (kt > qmaxw) continue;   // wave fully masked; barriers stay matched (top of loop)

    // ---- S^T = K · Q^T : C row = k (4g+reg), col = q (lam) ----
    f32x4 st[4];
#pragma unroll
    for (int ct = 0; ct < 4; ++ct) {
      st[ct] = (f32x4){0.f, 0.f, 0.f, 0.f};
#pragma unroll
      for (int dc = 0; dc < 4; ++dc) {
        const bf16x8 kf = *(const bf16x8*)(const void*)&Ks[(ct * 16 + lam) * KSP + dc * 32 + g * 8];
        st[ct] = __builtin_amdgcn_mfma_f32_16x16x32_bf16(kf, qf[dc], st[ct], 0, 0, 0);
      }
    }

    // ---- mask + scale (log2 domain), row-max over k ----
    float tmax = -1e30f;
#pragma unroll
    for (int ct = 0; ct < 4; ++ct) {
#pragma unroll
      for (int r = 0; r < 4; ++r) {
        const int kidx = kt + ct * 16 + 4 * g + r;
        const float x = (kidx >= klo && kidx <= qtok) ? st[ct][r] * SCL2 : -1e30f;
        st[ct][r] = x;
        tmax = fmaxf(tmax, x);
      }
    }
    tmax = fmaxf(tmax, __shfl_xor(tmax, 16));
    tmax = fmaxf(tmax, __shfl_xor(tmax, 32));
    float mn = fmaxf(fmaxf(m2, tmax), -60000.f);  // -60000: keeps exp2 args ~0 for virgin rows
    const float al = exp2f(m2 - mn);

    // ---- exp, row-sum, write P (bf16) to wave-private LDS (no barrier: same-wave RAW) ----
    float rs = 0.f;
#pragma unroll
    for (int ct = 0; ct < 4; ++ct) {
      const float p0 = exp2f(st[ct][0] - mn);
      const float p1 = exp2f(st[ct][1] - mn);
      const float p2 = exp2f(st[ct][2] - mn);
      const float p3 = exp2f(st[ct][3] - mn);
      rs += (p0 + p1) + (p2 + p3);
      *(u32x2*)(&Ps[w][lam * KP + ct * 16 + 4 * g]) = (u32x2){pk2(p0, p1), pk2(p2, p3)};
    }
    rs += __shfl_xor(rs, 16);
    rs += __shfl_xor(rs, 32);
    ll = ll * al + rs;
    m2 = mn;
#pragma unroll
    for (int i = 0; i < 8; ++i) {
      acc[i][0] *= al; acc[i][1] *= al; acc[i][2] *= al; acc[i][3] *= al;
    }

    // ---- O^T += V^T · P : A=V^T frag (row=d), B=P frag (col=q) ----
#pragma unroll
    for (int kc = 0; kc < 2; ++kc) {
      const bf16x8 pf = *(const bf16x8*)(const void*)&Ps[w][lam * KP + kc * 32 + g * 8];
#pragma unroll
      for (int dt = 0; dt < 8; ++dt) {
        const bf16x8 vf = *(const bf16x8*)(const void*)&Vt[(dt * 16 + lam) * KP + kc * 32 + g * 8];
        acc[dt] = __builtin_amdgcn_mfma_f32_16x16x32_bf16(vf, pf, acc[dt], 0, 0, 0);
      }
    }
  }

  // ---- epilogue: normalize, store (lane holds q=lam, 4 consecutive d per frag) ----
  const float inv = ll > 0.f ? 1.f / ll : 0.f;
  if (qtok < T) {
    float* op = Out + ((size_t)qtok * NHEADS + h) * HDIM + 4 * g;
#pragma unroll
    for (int dt = 0; dt < 8; ++dt) {
      f32x4 o = acc[dt];
      o[0] *= inv; o[1] *= inv; o[2] *= inv; o[3] *= inv;
      *(f32x4*)(op + dt * 16) = o;
    }
  }
}

extern "C" void kernel_launch(void* const* d_in, const int* in_sizes, int n_in,
                              void* d_out, int out_size, void* d_ws, size_t ws_size,
                              hipStream_t stream) {
  const float* Q = (const float*)d_in[0];
  const float* K = (const float*)d_in[1];
  const float* V = (const float*)d_in[2];
  const int* cu  = (const int*)d_in[3];   // seqlen_q (== seqlen_k)
  float* out = (float*)d_out;
  const int T = in_sizes[0] / (NHEADS * HDIM);
  const int ncu = in_sizes[3];
  dim3 grid((T + BQ - 1) / BQ, NHEADS);
  varlen_attn_mfma<<<grid, 256, 0, stream>>>(Q, K, V, cu, out, T, ncu);
}

// Round 3
// 237.104 us; speedup vs baseline: 2.8187x; 1.0384x over previous
//
#include <hip/hip_runtime.h>

#define NHEADS 16
#define HDIM 128
#define BQ 64          // q rows per block (16 per wave)
#define BK 64          // k tile width
#define KP 72          // Ps row stride (bf16): 144 B rows, 16B aligned
#define FKSP 136       // fallback kernel K stride
#define SCL2 0.12751740487817725f   // (1/sqrt(128)) * log2(e)

typedef float f32x4 __attribute__((ext_vector_type(4)));
typedef short bf16x8 __attribute__((ext_vector_type(8)));
typedef unsigned int u32x4 __attribute__((ext_vector_type(4)));
typedef unsigned int u32x2 __attribute__((ext_vector_type(2)));

// round-to-nearest-even f32 -> bf16, packed pair (finite randn inputs: no NaN guard)
__device__ __forceinline__ unsigned pk2(float a, float b) {
  unsigned ua = __builtin_bit_cast(unsigned, a);
  unsigned ub = __builtin_bit_cast(unsigned, b);
  ua = (ua + 0x7fffu + ((ua >> 16) & 1u)) >> 16;
  ub = (ub + 0x7fffu + ((ub >> 16) & 1u)) >> 16;
  return ua | (ub << 16);
}

// async global->LDS DMA, 16B per lane; lds dst must be wave-uniform base (+lane*16 by HW)
__device__ __forceinline__ void gld16(const void* g, void* l) {
  __builtin_amdgcn_global_load_lds((const __attribute__((address_space(1))) unsigned int*)g,
                                   (__attribute__((address_space(3))) unsigned int*)l,
                                   16, 0, 0);
}

// ---------------- pre-pass: K -> bf16 [h][t][d]; V -> bf16 transposed [h][d][t] ----------------
__global__ void prepass(const float* __restrict__ K, const float* __restrict__ V,
                        unsigned short* __restrict__ Kb, unsigned short* __restrict__ Vt,
                        int T, int nTc) {
  const int bx = (int)blockIdx.x;
  if (bx < T) {
    // K convert: rows = h*T + t (out-major); 16 chunks of 8 elems per row
    const int gid = bx * 256 + (int)threadIdx.x;
    const int c = gid & 15, row = gid >> 4;
    const int h = row / T, t = row - h * T;
    const float* src = K + ((size_t)t * NHEADS + h) * HDIM + c * 8;
    f32x4 a = *(const f32x4*)src;
    f32x4 b = *(const f32x4*)(src + 4);
    *(u32x4*)(Kb + (size_t)row * HDIM + c * 8) =
        (u32x4){pk2(a[0], a[1]), pk2(a[2], a[3]), pk2(b[0], b[1]), pk2(b[2], b[3])};
  } else {
    // V transpose: block covers (h, 256 tokens); wave w owns d in [32w,32w+32)
    const int bt = bx - T;
    const int tc = bt % nTc, h = bt / nTc;
    const int l = (int)threadIdx.x & 63, w = (int)threadIdx.x >> 6;
    const int t0 = tc * 256 + l * 4;
    unsigned short* ob = Vt + (size_t)h * HDIM * T;
    const float* p0 = V + (size_t)t0 * (NHEADS * HDIM) + h * HDIM;
#pragma unroll 4
    for (int dd = 0; dd < 32; dd += 2) {
      const int d = w * 32 + dd;
      float2 x0 = *(const float2*)(p0 + d);
      float2 x1 = *(const float2*)(p0 + NHEADS * HDIM + d);
      float2 x2 = *(const float2*)(p0 + 2 * NHEADS * HDIM + d);
      float2 x3 = *(const float2*)(p0 + 3 * NHEADS * HDIM + d);
      *(u32x2*)(ob + (size_t)d * T + t0) = (u32x2){pk2(x0.x, x1.x), pk2(x2.x, x3.x)};
      *(u32x2*)(ob + (size_t)(d + 1) * T + t0) = (u32x2){pk2(x0.y, x1.y), pk2(x2.y, x3.y)};
    }
  }
}

// ---------------- main kernel: async-staged, double-buffered, XOR-swizzled LDS ----------------
__launch_bounds__(256, 2)
__global__ void varlen_attn_v3(const float* __restrict__ Q,
                               const unsigned short* __restrict__ Kb,
                               const unsigned short* __restrict__ VtG,
                               const int* __restrict__ cu,
                               float* __restrict__ Out, int T, int ncu) {
  __shared__ __align__(16) unsigned short Ks[2][BK * HDIM];   // [k][d], 256B rows, chunk^= (k&7)
  __shared__ __align__(16) unsigned short Vt[2][HDIM * BK];   // [d][k], 128B rows, chunk^= (d&7)
  __shared__ __align__(16) unsigned short Ps[4][16 * KP];     // per-wave P [q][k]

  const int t = (int)threadIdx.x, w = t >> 6, l = t & 63;
  const int lam = l & 15, g = l >> 4;
  const int h = (int)blockIdx.y, q0 = (int)blockIdx.x * BQ;
  const int qtok = q0 + 16 * w + lam;
  const int qcl = qtok < T ? qtok : T - 1;

  int klo = 0, klo0 = 0;
  for (int i = 1; i < ncu - 1; ++i) {
    int c = cu[i];
    if (c <= qcl) klo = c;
    if (c <= q0) klo0 = c;
  }
  const int kstart = klo0 & ~(BK - 1);
  int kend = q0 + BQ - 1; if (kend > T - 1) kend = T - 1;
  const int qmaxw = q0 + 16 * w + 15;

  // ---- Q B-fragments from fp32 global (once per block) ----
  bf16x8 qf[4];
  {
    const float* qp = Q + ((size_t)qcl * NHEADS + h) * HDIM + g * 8;
#pragma unroll
    for (int dc = 0; dc < 4; ++dc) {
      f32x4 a = *(const f32x4*)(qp + dc * 32);
      f32x4 b = *(const f32x4*)(qp + dc * 32 + 4);
      union { u32x4 u; bf16x8 v; } cvt;
      cvt.u = (u32x4){pk2(a[0], a[1]), pk2(a[2], a[3]), pk2(b[0], b[1]), pk2(b[2], b[3])};
      qf[dc] = cvt.v;
    }
  }

  const unsigned short* KbH = Kb + (size_t)h * T * HDIM;
  const unsigned short* VtH = VtG + (size_t)h * HDIM * T;
  const int krow_b = 16 * w + (l >> 4);   // K: lane's LDS row (+4i), chunk l&15
  const int kchunk = l & 15;
  const int vrow_b = 32 * w + (l >> 3);   // V: lane's LDS row (+8i), chunk l&7
  const int vchunk = l & 7;

  auto stage = [&](int buf, int kt) {
#pragma unroll
    for (int i = 0; i < 4; ++i) {
      const int row = krow_b + 4 * i;
      int ktok = kt + row; if (ktok > T - 1) ktok = T - 1;
      gld16(KbH + (size_t)ktok * HDIM + ((kchunk ^ (row & 7)) * 8),
            (void*)&Ks[buf][(16 * w + 4 * i) * HDIM]);
    }
#pragma unroll
    for (int i = 0; i < 4; ++i) {
      const int d = vrow_b + 8 * i;
      gld16(VtH + (size_t)d * T + kt + ((vchunk ^ (d & 7)) * 8),
            (void*)&Vt[buf][(32 * w + 8 * i) * BK]);
    }
  };

  f32x4 acc[8];
#pragma unroll
  for (int i = 0; i < 8; ++i) acc[i] = (f32x4){0.f, 0.f, 0.f, 0.f};
  float m2 = -1e30f, ll = 0.f;

  int cur = 0;
  stage(0, kstart);
  for (int kt = kstart; kt <= kend; kt += BK) {
    __syncthreads();                       // drains prior tile's async loads (full compute phase behind them)
    if (kt + BK <= kend) stage(cur ^ 1, kt + BK);   // prefetch next tile into other buffer

    if (kt <= qmaxw) {
      const unsigned short* KsC = Ks[cur];
      const unsigned short* VtC = Vt[cur];

      // ---- S^T = K · Q^T ----
      f32x4 st[4];
#pragma unroll
      for (int ct = 0; ct < 4; ++ct) {
        st[ct] = (f32x4){0.f, 0.f, 0.f, 0.f};
#pragma unroll
        for (int dc = 0; dc < 4; ++dc) {
          const bf16x8 kf = *(const bf16x8*)(const void*)
              &KsC[(ct * 16 + lam) * HDIM + (((4 * dc + g) ^ (lam & 7)) * 8)];
          st[ct] = __builtin_amdgcn_mfma_f32_16x16x32_bf16(kf, qf[dc], st[ct], 0, 0, 0);
        }
      }

      // ---- mask + scale, row-max ----
      float tmax = -1e30f;
#pragma unroll
      for (int ct = 0; ct < 4; ++ct) {
#pragma unroll
        for (int r = 0; r < 4; ++r) {
          const int kidx = kt + ct * 16 + 4 * g + r;
          const float x = (kidx >= klo && kidx <= qtok) ? st[ct][r] * SCL2 : -1e30f;
          st[ct][r] = x;
          tmax = fmaxf(tmax, x);
        }
      }
      tmax = fmaxf(tmax, __shfl_xor(tmax, 16));
      tmax = fmaxf(tmax, __shfl_xor(tmax, 32));
      float mn = fmaxf(fmaxf(m2, tmax), -60000.f);
      const float al = exp2f(m2 - mn);

      float rs = 0.f;
#pragma unroll
      for (int ct = 0; ct < 4; ++ct) {
        const float p0 = exp2f(st[ct][0] - mn);
        const float p1 = exp2f(st[ct][1] - mn);
        const float p2 = exp2f(st[ct][2] - mn);
        const float p3 = exp2f(st[ct][3] - mn);
        rs += (p0 + p1) + (p2 + p3);
        *(u32x2*)(&Ps[w][lam * KP + ct * 16 + 4 * g]) = (u32x2){pk2(p0, p1), pk2(p2, p3)};
      }
      rs += __shfl_xor(rs, 16);
      rs += __shfl_xor(rs, 32);
      ll = ll * al + rs;
      m2 = mn;
#pragma unroll
      for (int i = 0; i < 8; ++i) {
        acc[i][0] *= al; acc[i][1] *= al; acc[i][2] *= al; acc[i][3] *= al;
      }

      // ---- O^T += V^T · P ----
#pragma unroll
      for (int kc = 0; kc < 2; ++kc) {
        const bf16x8 pf = *(const bf16x8*)(const void*)&Ps[w][lam * KP + kc * 32 + g * 8];
#pragma unroll
        for (int dt = 0; dt < 8; ++dt) {
          const bf16x8 vf = *(const bf16x8*)(const void*)
              &VtC[(dt * 16 + lam) * BK + (((4 * kc + g) ^ (lam & 7)) * 8)];
          acc[dt] = __builtin_amdgcn_mfma_f32_16x16x32_bf16(vf, pf, acc[dt], 0, 0, 0);
        }
      }
    }
    cur ^= 1;
  }

  const float inv = ll > 0.f ? 1.f / ll : 0.f;
  if (qtok < T) {
    float* op = Out + ((size_t)qtok * NHEADS + h) * HDIM + 4 * g;
#pragma unroll
    for (int dt = 0; dt < 8; ++dt) {
      f32x4 o = acc[dt];
      o[0] *= inv; o[1] *= inv; o[2] *= inv; o[3] *= inv;
      *(f32x4*)(op + dt * 16) = o;
    }
  }
}

// ---------------- fallback (round-2 kernel) if workspace too small ----------------
__launch_bounds__(256, 3)
__global__ void varlen_attn_fb(const float* __restrict__ Q,
                               const float* __restrict__ K,
                               const float* __restrict__ V,
                               const int* __restrict__ cu,
                               float* __restrict__ Out, int T, int ncu) {
  __shared__ __align__(16) unsigned short Ksf[BK * FKSP];
  __shared__ __align__(16) unsigned short Vtf[HDIM * KP];
  __shared__ __align__(16) unsigned short Psf[4][16 * KP];

  const int t = (int)threadIdx.x, w = t >> 6, l = t & 63;
  const int lam = l & 15, g = l >> 4;
  const int h = (int)blockIdx.y, q0 = (int)blockIdx.x * BQ;
  const int qtok = q0 + 16 * w + lam;
  const int qcl = qtok < T ? qtok : T - 1;
  int klo = 0, klo0 = 0;
  for (int i = 1; i < ncu - 1; ++i) {
    int c = cu[i];
    if (c <= qcl) klo = c;
    if (c <= q0) klo0 = c;
  }
  const int kstart = klo0 & ~(BK - 1);
  int kend = q0 + BQ - 1; if (kend > T - 1) kend = T - 1;
  const int qmaxw = q0 + 16 * w + 15;
  bf16x8 qf[4];
  {
    const float* qp = Q + ((size_t)qcl * NHEADS + h) * HDIM + g * 8;
#pragma unroll
    for (int dc = 0; dc < 4; ++dc) {
      f32x4 a = *(const f32x4*)(qp + dc * 32);
      f32x4 b = *(const f32x4*)(qp + dc * 32 + 4);
      union { u32x4 u; bf16x8 v; } cvt;
      cvt.u = (u32x4){pk2(a[0], a[1]), pk2(a[2], a[3]), pk2(b[0], b[1]), pk2(b[2], b[3])};
      qf[dc] = cvt.v;
    }
  }
  f32x4 acc[8];
#pragma unroll
  for (int i = 0; i < 8; ++i) acc[i] = (f32x4){0.f, 0.f, 0.f, 0.f};
  float m2 = -1e30f, ll = 0.f;
  for (int kt = kstart; kt <= kend; kt += BK) {
    __syncthreads();
    {
      const int row = t >> 2, db = (t & 3) * 32;
      int ktok = kt + row; if (ktok > T - 1) ktok = T - 1;
      const float* kp = K + ((size_t)ktok * NHEADS + h) * HDIM + db;
      unsigned short* dst = &Ksf[row * FKSP + db];
#pragma unroll
      for (int i = 0; i < 4; ++i) {
        f32x4 a = *(const f32x4*)(kp + i * 8);
        f32x4 b = *(const f32x4*)(kp + i * 8 + 4);
        *(u32x4*)(dst + i * 8) =
            (u32x4){pk2(a[0], a[1]), pk2(a[2], a[3]), pk2(b[0], b[1]), pk2(b[2], b[3])};
      }
    }
#pragma unroll
    for (int c = 0; c < 2; ++c) {
      const int kb = kt + 16 * w + 8 * c;
#pragma unroll
      for (int dh = 0; dh < 2; ++dh) {
        const int d = dh * 64 + l;
        float vv[8];
#pragma unroll
        for (int j = 0; j < 8; ++j) {
          int ktok = kb + j; if (ktok > T - 1) ktok = T - 1;
          vv[j] = V[((size_t)ktok * NHEADS + h) * HDIM + d];
        }
        *(u32x4*)(&Vtf[d * KP + 16 * w + 8 * c]) =
            (u32x4){pk2(vv[0], vv[1]), pk2(vv[2], vv[3]), pk2(vv[4], vv[5]), pk2(vv[6], vv[7])};
      }
    }
    __syncthreads();
    if (kt > qmaxw) continue;
    f32x4 st[4];
#pragma unroll
    for (int ct = 0; ct < 4; ++ct) {
      st[ct] = (f32x4){0.f, 0.f, 0.f, 0.f};
#pragma unroll
      for (int dc = 0; dc < 4; ++dc) {
        const bf16x8 kf = *(const bf16x8*)(const void*)&Ksf[(ct * 16 + lam) * FKSP + dc * 32 + g * 8];
        st[ct] = __builtin_amdgcn_mfma_f32_16x16x32_bf16(kf, qf[dc], st[ct], 0, 0, 0);
      }
    }
    float tmax = -1e30f;
#pragma unroll
    for (int ct = 0; ct < 4; ++ct) {
#pragma unroll
      for (int r = 0; r < 4; ++r) {
        const int kidx = kt + ct * 16 + 4 * g + r;
        const float x = (kidx >= klo && kidx <= qtok) ? st[ct][r] * SCL2 : -1e30f;
        st[ct][r] = x;
        tmax = fmaxf(tmax, x);
      }
    }
    tmax = fmaxf(tmax, __shfl_xor(tmax, 16));
    tmax = fmaxf(tmax, __shfl_xor(tmax, 32));
    float mn = fmaxf(fmaxf(m2, tmax), -60000.f);
    const float al = exp2f(m2 - mn);
    float rs = 0.f;
#pragma unroll
    for (int ct = 0; ct < 4; ++ct) {
      const float p0 = exp2f(st[ct][0] - mn);
      const float p1 = exp2f(st[ct][1] - mn);
      const float p2 = exp2f(st[ct][2] - mn);
      const float p3 = exp2f(st[ct][3] - mn);
      rs += (p0 + p1) + (p2 + p3);
      *(u32x2*)(&Psf[w][lam * KP + ct * 16 + 4 * g]) = (u32x2){pk2(p0, p1), pk2(p2, p3)};
    }
    rs += __shfl_xor(rs, 16);
    rs += __shfl_xor(rs, 32);
    ll = ll * al + rs;
    m2 = mn;
#pragma unroll
    for (int i = 0; i < 8; ++i) {
      acc[i][0] *= al; acc[i][1] *= al; acc[i][2] *= al; acc[i][3] *= al;
    }
#pragma unroll
    for (int kc = 0; kc < 2; ++kc) {
      const bf16x8 pf = *(const bf16x8*)(const void*)&Psf[w][lam * KP + kc * 32 + g * 8];
#pragma unroll
      for (int dt = 0; dt < 8; ++dt) {
        const bf16x8 vf = *(const bf16x8*)(const void*)&Vtf[(dt * 16 + lam) * KP + kc * 32 + g * 8];
        acc[dt] = __builtin_amdgcn_mfma_f32_16x16x32_bf16(vf, pf, acc[dt], 0, 0, 0);
      }
    }
  }
  const float inv = ll > 0.f ? 1.f / ll : 0.f;
  if (qtok < T) {
    float* op = Out + ((size_t)qtok * NHEADS + h) * HDIM + 4 * g;
#pragma unroll
    for (int dt = 0; dt < 8; ++dt) {
      f32x4 o = acc[dt];
      o[0] *= inv; o[1] *= inv; o[2] *= inv; o[3] *= inv;
      *(f32x4*)(op + dt * 16) = o;
    }
  }
}

extern "C" void kernel_launch(void* const* d_in, const int* in_sizes, int n_in,
                              void* d_out, int out_size, void* d_ws, size_t ws_size,
                              hipStream_t stream) {
  const float* Q = (const float*)d_in[0];
  const float* K = (const float*)d_in[1];
  const float* V = (const float*)d_in[2];
  const int* cu  = (const int*)d_in[3];
  float* out = (float*)d_out;
  const int T = in_sizes[0] / (NHEADS * HDIM);
  const int ncu = in_sizes[3];
  const size_t need = (size_t)2 * NHEADS * T * HDIM * sizeof(unsigned short);  // Kb + Vt
  if (ws_size >= need && (T % 256) == 0) {
    unsigned short* Kb = (unsigned short*)d_ws;
    unsigned short* Vt = Kb + (size_t)NHEADS * T * HDIM;
    const int nTc = T / 256;
    prepass<<<dim3(T + nTc * NHEADS), 256, 0, stream>>>(K, V, Kb, Vt, T, nTc);
    dim3 grid(T / BQ, NHEADS);
    varlen_attn_v3<<<grid, 256, 0, stream>>>(Q, Kb, Vt, cu, out, T, ncu);
  } else {
    dim3 grid((T + BQ - 1) / BQ, NHEADS);
    varlen_attn_fb<<<grid, 256, 0, stream>>>(Q, K, V, cu, out, T, ncu);
  }
}